// Round 20
// baseline (291.229 us; speedup 1.0000x reference)
//
#include <hip/hip_runtime.h>
#include <hip/hip_bf16.h>
#include <stdint.h>
#include <math.h>

#define H_ 16
#define HD_ 128
#define RD_ 64
#define CD_ 64
#define DM_ 2048
#define QR_ 512
#define DL_ 512
#define B_ 2
#define T_ 2048
#define M_TOT (B_*T_)

typedef __attribute__((ext_vector_type(8))) short short8;
typedef __attribute__((ext_vector_type(4))) float f32x4;
typedef __attribute__((ext_vector_type(16))) float f32x16;

__device__ __forceinline__ unsigned short f2b_hw(float f){
  __hip_bfloat16 h = __float2bfloat16(f);
  union { __hip_bfloat16 h; unsigned short u; } c; c.h = h; return c.u;
}
__device__ __forceinline__ float b2f(unsigned short b){
  union { unsigned u; float f; } a; a.u = ((unsigned)b) << 16;
  return a.f;
}
__device__ __forceinline__ unsigned pack2(float lo, float hi){
  __hip_bfloat162 h2 = __float22bfloat162_rn(make_float2(lo, hi));
  union { __hip_bfloat162 h; unsigned u; } c; c.h = h2; return c.u;
}

#define GLOAD16(g, l) __builtin_amdgcn_global_load_lds( \
    (__attribute__((address_space(1))) void*)(g), \
    (__attribute__((address_space(3))) void*)(l), 16, 0, 0)

struct TTe { const float* src; unsigned short* dst; int K, N, blk0; };
struct TT8 { TTe e[8]; };

// ---------------- fused prep: x cast | rope table | 8 weight transposes ----------------
__global__ void prep_all(const float* __restrict__ src,
                         unsigned short* __restrict__ dst, int n,
                         float2* __restrict__ tab, TT8 tt){
  __shared__ float tile[32][33];
  int bid = blockIdx.x;
  int tid = threadIdx.x;
  if (bid < 8192) {
    int i = (bid * 256 + tid) * 4;
    if (i < n){
      float4 v = *(const float4*)(src + i);
      ushort4 o;
      o.x = f2b_hw(v.x); o.y = f2b_hw(v.y); o.z = f2b_hw(v.z); o.w = f2b_hw(v.w);
      *(ushort4*)(dst + i) = o;
    }
    return;
  }
  if (bid < 8448) {
    int idx = (bid - 8192) * 256 + tid;   // 64K entries
    int t = idx >> 5, j = idx & 31;
    float invf = exp2f(-(float)j * 0.4152410118750f);
    float fr = (float)t * invf;
    float s, c;
    sincosf(fr, &s, &c);
    tab[idx] = make_float2(c, s);
    return;
  }
  int loc = bid - 8448;
  const float* wsrc = tt.e[0].src;
  unsigned short* wdst = tt.e[0].dst;
  int K = tt.e[0].K, N = tt.e[0].N, l2 = loc;
  #pragma unroll
  for (int j = 1; j < 8; j++){
    if (loc >= tt.e[j].blk0){
      wsrc = tt.e[j].src; wdst = tt.e[j].dst;
      K = tt.e[j].K; N = tt.e[j].N; l2 = loc - tt.e[j].blk0;
    }
  }
  int cols = N / 32;
  int n0 = (l2 % cols) * 32, k0 = (l2 / cols) * 32;
  int tx = tid & 7, ty = tid >> 3;
  float4 v = *(const float4*)&wsrc[(size_t)(k0 + ty) * N + n0 + tx * 4];
  tile[ty][tx * 4 + 0] = v.x;
  tile[ty][tx * 4 + 1] = v.y;
  tile[ty][tx * 4 + 2] = v.z;
  tile[ty][tx * 4 + 3] = v.w;
  __syncthreads();
  ushort4 o;
  o.x = f2b_hw(tile[tx * 4 + 0][ty]);
  o.y = f2b_hw(tile[tx * 4 + 1][ty]);
  o.z = f2b_hw(tile[tx * 4 + 2][ty]);
  o.w = f2b_hw(tile[tx * 4 + 3][ty]);
  *(ushort4*)&wdst[(size_t)(n0 + ty) * K + k0 + tx * 4] = o;
}

// ---------------- 256x256 / BK=64 / 8-wave GEMM with counted vmcnt + st_16x32 swizzle ------
// MODE 4: N=3072 down-proj: cols<1024 -> latent linear; else fused-RoPE -> qh(Cv2)/kh(Cv3)
//         (q-rope pre-scaled by SC)
// MODE 5: N=4096 up-proj: cols<1024 -> qh content (pre-scaled by SC); <2048 -> kh; else vt^T
template<int MODE>
__global__ __launch_bounds__(512, 1) void gemm256(
    const unsigned short* __restrict__ A, int lda,
    const unsigned short* __restrict__ Bt,
    void* __restrict__ Cv, void* __restrict__ Cv2, void* __restrict__ Cv3,
    const float2* __restrict__ tab,
    int ldc, int N, int K)
{
  __shared__ __align__(16) unsigned short lds[65536];   // 128 KB
  char* ldsb = (char*)lds;

  const int tid = threadIdx.x;
  const int lane = tid & 63, w = tid >> 6;
  const int wm = w >> 2, wn = w & 3;
  const int l15 = lane & 15, kg = lane >> 4;

  int gx = gridDim.x;
  int nwg = gx * gridDim.y;
  int lin = blockIdx.x + gx * blockIdx.y;
  int q8 = nwg >> 3;
  int nl = (lin & 7) * q8 + (lin >> 3);
  int m0 = (nl / gx) * 256, n0 = (nl % gx) * 256;

  const unsigned short* Aeff = A;
  if (MODE == 5 && n0 >= 1024) Aeff = A + 512;

  const int srow = tid >> 3;
  const int scol = ((((tid & 7) << 4) ^ (((tid >> 5) & 1) << 5)) >> 1);
  const int aswz = ((l15 >> 2) & 1) << 5;

#define STG(bufb, kt) do {                                                     \
    int k0_ = (kt) * 64;                                                       \
    _Pragma("unroll")                                                          \
    for (int h_ = 0; h_ < 2; h_++)                                             \
      _Pragma("unroll")                                                        \
      for (int i_ = 0; i_ < 2; i_++) {                                         \
        GLOAD16(Aeff + (size_t)(m0 + h_*128 + i_*64 + srow) * lda + k0_ + scol,\
                ldsb + (bufb)*65536 + h_*16384 + i_*8192 + tid*16);            \
        GLOAD16(Bt + (size_t)(n0 + h_*128 + i_*64 + srow) * K + k0_ + scol,    \
                ldsb + (bufb)*65536 + 32768 + h_*16384 + i_*8192 + tid*16);    \
      }                                                                        \
  } while (0)

  f32x4 acc[8][4];
  #pragma unroll
  for (int i = 0; i < 8; i++)
    #pragma unroll
    for (int j = 0; j < 4; j++)
      acc[i][j] = (f32x4){0.f, 0.f, 0.f, 0.f};

  const int nK = K >> 6;
  STG(0, 0);
  STG(1, 1);

  for (int t = 0; t < nK; t++) {
    const int c = t & 1;
    if (t < nK - 1) { asm volatile("s_waitcnt vmcnt(8)" ::: "memory"); }
    else            { asm volatile("s_waitcnt vmcnt(0)" ::: "memory"); }
    __builtin_amdgcn_s_barrier();
    __builtin_amdgcn_sched_barrier(0);

    const char* bufA = ldsb + c * 65536 + wm * 16384;
    const char* bufB = ldsb + c * 65536 + 32768;

    short8 bfr[4][2];
    #pragma unroll
    for (int nf = 0; nf < 4; nf++) {
      int nr = wn * 64 + nf * 16 + l15;
      #pragma unroll
      for (int kk = 0; kk < 2; kk++) {
        int L = (nr & 127) * 128 + kk * 64 + kg * 16;
        bfr[nf][kk] = *(const short8*)(bufB + (nr >> 7) * 16384 + (L ^ aswz));
      }
    }
    __builtin_amdgcn_s_setprio(1);
    #pragma unroll
    for (int mh = 0; mh < 2; mh++) {
      short8 afr[4][2];
      #pragma unroll
      for (int q = 0; q < 4; q++) {
        int mf = mh * 4 + q;
        #pragma unroll
        for (int kk = 0; kk < 2; kk++) {
          int L = (mf * 16 + l15) * 128 + kk * 64 + kg * 16;
          afr[q][kk] = *(const short8*)(bufA + (L ^ aswz));
        }
      }
      #pragma unroll
      for (int q = 0; q < 4; q++)
        #pragma unroll
        for (int nf = 0; nf < 4; nf++)
          #pragma unroll
          for (int kk = 0; kk < 2; kk++)
            acc[mh*4+q][nf] = __builtin_amdgcn_mfma_f32_16x16x32_bf16(
                afr[q][kk], bfr[nf][kk], acc[mh*4+q][nf], 0, 0, 0);
    }
    __builtin_amdgcn_s_setprio(0);
    __builtin_amdgcn_sched_barrier(0);
    __builtin_amdgcn_s_barrier();
    __builtin_amdgcn_sched_barrier(0);
    if (t + 2 < nK) STG(c, t + 2);
  }
#undef STG

  if (MODE == 4) {
    if (n0 < 1024) {
      unsigned short* C = (unsigned short*)Cv;
      #pragma unroll
      for (int mf = 0; mf < 8; mf++)
        #pragma unroll
        for (int nf = 0; nf < 4; nf++)
          #pragma unroll
          for (int rr = 0; rr < 4; rr++) {
            int row = m0 + wm * 128 + mf * 16 + kg * 4 + rr;
            int col = n0 + wn * 64 + nf * 16 + l15;
            C[(size_t)row * ldc + col] = f2b_hw(acc[mf][nf][rr]);
          }
    } else {
      const bool isq = (n0 < 2048);
      unsigned short* dst = (unsigned short*)(isq ? Cv2 : Cv3);
      const float qsc = isq ? 0.12751743f : 1.0f;   // fold softmax scale into q
      int hbase = ((n0 - (isq ? 1024 : 2048)) >> 6) + wn;
      #pragma unroll
      for (int nf = 0; nf < 2; nf++) {
        int jr = nf * 16 + l15;
        #pragma unroll
        for (int mf = 0; mf < 8; mf++)
          #pragma unroll
          for (int rr = 0; rr < 4; rr++) {
            int gr = m0 + wm * 128 + mf * 16 + kg * 4 + rr;
            int tt = gr & (T_ - 1), bb = gr >> 11;
            float2 cs = tab[tt * 32 + jr];
            float x1 = acc[mf][nf][rr], x2 = acc[mf][nf + 2][rr];
            size_t base = ((size_t)(bb * H_ + hbase) * T_ + tt) * 128 + 64;
            dst[base + jr]      = f2b_hw((x1 * cs.x - x2 * cs.y) * qsc);
            dst[base + jr + 32] = f2b_hw((x1 * cs.y + x2 * cs.x) * qsc);
          }
      }
    }
  } else { // MODE 5
    if (n0 < 2048) {
      unsigned short* dstp = (unsigned short*)(n0 < 1024 ? Cv : Cv2);
      const float qsc = (n0 < 1024) ? 0.12751743f : 1.0f;  // q content pre-scaled
      int cb0 = n0 - (n0 < 1024 ? 0 : 1024);
      #pragma unroll
      for (int nf = 0; nf < 4; nf++) {
        int colb = cb0 + wn * 64 + nf * 16 + l15;
        int h = colb >> 6, d = colb & 63;
        #pragma unroll
        for (int mf = 0; mf < 8; mf++)
          #pragma unroll
          for (int rr = 0; rr < 4; rr++) {
            int gr = m0 + wm * 128 + mf * 16 + kg * 4 + rr;
            size_t idx = ((size_t)((gr >> 11) * H_ + h) * T_ + (gr & (T_-1))) * 128 + d;
            dstp[idx] = f2b_hw(acc[mf][nf][rr] * qsc);
          }
      }
    } else {
      unsigned short* vtp = (unsigned short*)Cv3;
      #pragma unroll
      for (int nf = 0; nf < 4; nf++) {
        int c2 = n0 + wn * 64 + nf * 16 + l15 - 2048;
        int h = c2 >> 7, d = c2 & 127;
        #pragma unroll
        for (int mf = 0; mf < 8; mf++) {
          int gr0 = m0 + wm * 128 + mf * 16 + kg * 4;
          int bb = gr0 >> 11, t0 = gr0 & (T_-1);
          ushort4 o;
          o.x = f2b_hw(acc[mf][nf][0]); o.y = f2b_hw(acc[mf][nf][1]);
          o.z = f2b_hw(acc[mf][nf][2]); o.w = f2b_hw(acc[mf][nf][3]);
          *(ushort4*)&vtp[((size_t)(bb * H_ + h) * 128 + d) * T_ + t0] = o;
        }
      }
    }
  }
}

// ---------------- output GEMM: 128x256 / BK=64 / 8-wave, f32 linear out ----------------
__global__ __launch_bounds__(512, 1) void gemm_out(
    const unsigned short* __restrict__ A, int lda,
    const unsigned short* __restrict__ Bt,
    float* __restrict__ C, int ldc, int K)
{
  __shared__ __align__(16) unsigned short lds[49152];
  char* ldsb = (char*)lds;

  const int tid = threadIdx.x;
  const int lane = tid & 63, w = tid >> 6;
  const int wm = w >> 2, wn = w & 3;
  const int l15 = lane & 15, kg = lane >> 4;

  int gx = gridDim.x;
  int nwg = gx * gridDim.y;
  int lin = blockIdx.x + gx * blockIdx.y;
  int q8 = nwg >> 3;
  int nl = (lin & 7) * q8 + (lin >> 3);
  int m0 = (nl / gx) * 128, n0 = (nl % gx) * 256;

  const int srow = tid >> 3;
  const int scol = ((((tid & 7) << 4) ^ (((tid >> 5) & 1) << 5)) >> 1);
  const int aswz = ((l15 >> 2) & 1) << 5;

#define STG(bufb, kt) do {                                                     \
    int k0_ = (kt) * 64;                                                       \
    _Pragma("unroll")                                                          \
    for (int i_ = 0; i_ < 2; i_++)                                             \
      GLOAD16(A + (size_t)(m0 + i_*64 + srow) * lda + k0_ + scol,              \
              ldsb + (bufb)*49152 + i_*8192 + tid*16);                         \
    _Pragma("unroll")                                                          \
    for (int i_ = 0; i_ < 4; i_++)                                             \
      GLOAD16(Bt + (size_t)(n0 + i_*64 + srow) * K + k0_ + scol,               \
              ldsb + (bufb)*49152 + 16384 + i_*8192 + tid*16);                 \
  } while (0)

  f32x4 acc[4][4];
  #pragma unroll
  for (int i = 0; i < 4; i++)
    #pragma unroll
    for (int j = 0; j < 4; j++)
      acc[i][j] = (f32x4){0.f, 0.f, 0.f, 0.f};

  const int nK = K >> 6;
  STG(0, 0);
  STG(1, 1);

  for (int t = 0; t < nK; t++) {
    const int c = t & 1;
    if (t < nK - 1) { asm volatile("s_waitcnt vmcnt(6)" ::: "memory"); }
    else            { asm volatile("s_waitcnt vmcnt(0)" ::: "memory"); }
    __builtin_amdgcn_s_barrier();
    __builtin_amdgcn_sched_barrier(0);

    const char* bufA = ldsb + c * 49152 + wm * 8192;
    const char* bufB = ldsb + c * 49152 + 16384;

    short8 bfr[4][2];
    #pragma unroll
    for (int nf = 0; nf < 4; nf++) {
      int nr = wn * 64 + nf * 16 + l15;
      #pragma unroll
      for (int kk = 0; kk < 2; kk++) {
        int L = (nr & 63) * 128 + kk * 64 + kg * 16;
        bfr[nf][kk] = *(const short8*)(bufB + (nr >> 6) * 8192 + (L ^ aswz));
      }
    }
    short8 afr[4][2];
    #pragma unroll
    for (int mf = 0; mf < 4; mf++)
      #pragma unroll
      for (int kk = 0; kk < 2; kk++) {
        int L = (mf * 16 + l15) * 128 + kk * 64 + kg * 16;
        afr[mf][kk] = *(const short8*)(bufA + (L ^ aswz));
      }
    __builtin_amdgcn_s_setprio(1);
    #pragma unroll
    for (int mf = 0; mf < 4; mf++)
      #pragma unroll
      for (int nf = 0; nf < 4; nf++)
        #pragma unroll
        for (int kk = 0; kk < 2; kk++)
          acc[mf][nf] = __builtin_amdgcn_mfma_f32_16x16x32_bf16(
              afr[mf][kk], bfr[nf][kk], acc[mf][nf], 0, 0, 0);
    __builtin_amdgcn_s_setprio(0);
    __builtin_amdgcn_sched_barrier(0);
    __builtin_amdgcn_s_barrier();
    __builtin_amdgcn_sched_barrier(0);
    if (t + 2 < nK) STG(c, t + 2);
  }
#undef STG

  #pragma unroll
  for (int mf = 0; mf < 4; mf++)
    #pragma unroll
    for (int nf = 0; nf < 4; nf++)
      #pragma unroll
      for (int rr = 0; rr < 4; rr++) {
        int row = m0 + wm * 64 + mf * 16 + kg * 4 + rr;
        int col = n0 + wn * 64 + nf * 16 + l15;
        C[(size_t)row * ldc + col] = acc[mf][nf][rr];
      }
}

// ---------------- causal flash attention: R7 pipeline + 4-way QK^T ILP (q pre-scaled) --------
__global__ __launch_bounds__(256, 2) void attn_fwd8(
    const unsigned short* __restrict__ qh,
    const unsigned short* __restrict__ kh,
    const unsigned short* __restrict__ vt,
    unsigned short* __restrict__ ao)
{
  __shared__ __align__(16) unsigned short lds[4 * 8192];

  const int tid  = threadIdx.x;
  const int lane = tid & 63, w = tid >> 6;
  const int l31  = lane & 31, hi = lane >> 5;
  const int bh = blockIdx.y;
  const int b  = bh >> 4, hd = bh & 15;
  int qt = blockIdx.x;
  if (bh >= 16) qt = 15 - qt;
  const int q0w   = qt * 128 + w * 32;
  const int qg    = q0w + l31;
  const int qmaxw = q0w + 31;
  const int nt    = 2 * qt + 2;

  const unsigned short* Qg = qh + (size_t)bh * T_ * 128;
  const unsigned short* Kg = kh + (size_t)bh * T_ * 128;
  const unsigned short* Vg = vt + (size_t)bh * 128 * T_;

  short8 qf[8];
  #pragma unroll
  for (int kc = 0; kc < 8; kc++)
    qf[kc] = *(const short8*)&Qg[(size_t)qg * 128 + kc * 16 + hi * 8];

  f32x16 accO[4];
  #pragma unroll
  for (int sb = 0; sb < 4; sb++)
    #pragma unroll
    for (int r = 0; r < 16; r++) accO[sb][r] = 0.f;

  float m = -1e30f, lsum = 0.f;
  // q is pre-scaled by (1/sqrt(128))*log2(e) at projection time -> scores already exp2-domain

  int krow[4], kwof[4], vrow[4], vwof[4];
  #pragma unroll
  for (int jj = 0; jj < 4; jj++){
    int r_ = (w * 4 + jj) * 4 + (lane >> 4);
    krow[jj] = r_;
    kwof[jj] = r_ * 128 + ((((lane & 15) * 16) ^ ((r_ & 7) << 4)) >> 1);
    int d_ = (w * 4 + jj) * 8 + (lane >> 3);
    vrow[jj] = d_;
    vwof[jj] = d_ * 64 + ((((lane & 7) * 16) ^ ((d_ & 7) << 4)) >> 1);
  }
  const int kcol = (lane & 15) * 8;
  const int vcol = (lane & 7) * 8;

  uint4 kst[4], vst[4];

#define REG_LOAD(kvt) do {                                                    \
    int kv0s = (kvt) * 64;                                                    \
    _Pragma("unroll")                                                         \
    for (int j_ = 0; j_ < 4; j_++) {                                          \
      kst[j_] = *(const uint4*)&Kg[(size_t)(kv0s + krow[j_]) * 128 + kcol];   \
      vst[j_] = *(const uint4*)&Vg[(size_t)vrow[j_] * T_ + kv0s + vcol];      \
    }                                                                         \
  } while (0)

#define DS_WRITE(bufi) do {                                                   \
    unsigned short* ksb_ = lds + (bufi) * 8192;                               \
    unsigned short* vsb_ = lds + 16384 + (bufi) * 8192;                       \
    _Pragma("unroll")                                                         \
    for (int j_ = 0; j_ < 4; j_++) {                                          \
      *(uint4*)&ksb_[kwof[j_]] = kst[j_];                                     \
      *(uint4*)&vsb_[vwof[j_]] = vst[j_];                                     \
    }                                                                         \
  } while (0)

  REG_LOAD(0);
  DS_WRITE(0);
  if (nt > 1) REG_LOAD(1);
  asm volatile("s_waitcnt lgkmcnt(0)" ::: "memory");
  __builtin_amdgcn_s_barrier();
  __builtin_amdgcn_sched_barrier(0);

  for (int t = 0; t < nt; t++) {
    const int cur = t & 1;
    if (t + 1 < nt) DS_WRITE(cur ^ 1);
    if (t + 2 < nt) REG_LOAD(t + 2);
    const int kv0 = t * 64;
    if (kv0 <= qmaxw) {
      const unsigned short* Kb = lds + cur * 8192;
      const unsigned short* Vb = lds + 16384 + cur * 8192;

      // ---- QK^T (swapped), 4 independent MFMA chains (a/b split) ----
      f32x16 sa0, sa1, sb0, sb1;
      #pragma unroll
      for (int r = 0; r < 16; r++) { sa0[r] = 0.f; sa1[r] = 0.f; sb0[r] = 0.f; sb1[r] = 0.f; }
      __builtin_amdgcn_s_setprio(1);
      #pragma unroll
      for (int kc = 0; kc < 8; kc += 2) {
        int co0 = (kc * 32 + hi * 16);
        int co1 = ((kc + 1) * 32 + hi * 16);
        int r0 = l31, r1 = 32 + l31;
        short8 kf0a = *(const short8*)&Kb[r0 * 128 + ((co0 ^ ((r0 & 7) << 4)) >> 1)];
        short8 kf1a = *(const short8*)&Kb[r1 * 128 + ((co0 ^ ((r1 & 7) << 4)) >> 1)];
        short8 kf0b = *(const short8*)&Kb[r0 * 128 + ((co1 ^ ((r0 & 7) << 4)) >> 1)];
        short8 kf1b = *(const short8*)&Kb[r1 * 128 + ((co1 ^ ((r1 & 7) << 4)) >> 1)];
        sa0 = __builtin_amdgcn_mfma_f32_32x32x16_bf16(kf0a, qf[kc], sa0, 0, 0, 0);
        sa1 = __builtin_amdgcn_mfma_f32_32x32x16_bf16(kf1a, qf[kc], sa1, 0, 0, 0);
        sb0 = __builtin_amdgcn_mfma_f32_32x32x16_bf16(kf0b, qf[kc + 1], sb0, 0, 0, 0);
        sb1 = __builtin_amdgcn_mfma_f32_32x32x16_bf16(kf1b, qf[kc + 1], sb1, 0, 0, 0);
      }
      __builtin_amdgcn_s_setprio(0);
      sa0 += sb0;
      sa1 += sb1;

      float p0[16], p1[16];
      float pmax = -1e30f;
      bool needMask = (kv0 + 63 > q0w);
      if (needMask) {
        #pragma unroll
        for (int r = 0; r < 16; r++) {
          int crow = (r & 3) + 8 * (r >> 2) + 4 * hi;
          float v0 = sa0[r];
          float v1 = sa1[r];
          if (kv0 + crow > qg)      v0 = -1e30f;
          if (kv0 + 32 + crow > qg) v1 = -1e30f;
          p0[r] = v0; p1[r] = v1;
          pmax = fmaxf(pmax, fmaxf(v0, v1));
        }
      } else {
        #pragma unroll
        for (int r = 0; r < 16; r++) {
          float v0 = sa0[r];
          float v1 = sa1[r];
          p0[r] = v0; p1[r] = v1;
          pmax = fmaxf(pmax, fmaxf(v0, v1));
        }
      }
      pmax = fmaxf(pmax, __shfl_xor(pmax, 32, 64));
      if (!__all(pmax <= m + 8.f)) {     // T13 defer-max
        float mn  = fmaxf(m, pmax);
        float fac = exp2f(m - mn);
        m = mn;
        lsum *= fac;
        #pragma unroll
        for (int sb = 0; sb < 4; sb++)
          #pragma unroll
          for (int r = 0; r < 16; r++) accO[sb][r] *= fac;
      }
      float ls = 0.f;
      #pragma unroll
      for (int r = 0; r < 16; r++) {
        p0[r] = exp2f(p0[r] - m);
        p1[r] = exp2f(p1[r] - m);
        ls += p0[r] + p1[r];
      }
      ls += __shfl_xor(ls, 32, 64);
      lsum += ls;

      #pragma unroll
      for (int kc2 = 0; kc2 < 4; kc2++) {
        unsigned A01, A23, B01, B23;
        if (kc2 == 0) { A01 = pack2(p0[0], p0[1]);  A23 = pack2(p0[2], p0[3]);
                        B01 = pack2(p0[4], p0[5]);  B23 = pack2(p0[6], p0[7]); }
        else if (kc2 == 1) { A01 = pack2(p0[8], p0[9]);   A23 = pack2(p0[10], p0[11]);
                             B01 = pack2(p0[12], p0[13]); B23 = pack2(p0[14], p0[15]); }
        else if (kc2 == 2) { A01 = pack2(p1[0], p1[1]);  A23 = pack2(p1[2], p1[3]);
                             B01 = pack2(p1[4], p1[5]);  B23 = pack2(p1[6], p1[7]); }
        else { A01 = pack2(p1[8], p1[9]);   A23 = pack2(p1[10], p1[11]);
               B01 = pack2(p1[12], p1[13]); B23 = pack2(p1[14], p1[15]); }
        asm("v_permlane32_swap_b32 %0, %1" : "+v"(A01), "+v"(B01));
        asm("v_permlane32_swap_b32 %0, %1" : "+v"(A23), "+v"(B23));
        union { unsigned u[4]; short8 v; } pk;
        pk.u[0] = A01; pk.u[1] = A23; pk.u[2] = B01; pk.u[3] = B23;
        short8 pa = pk.v;
        __builtin_amdgcn_s_setprio(1);
        #pragma unroll
        for (int sb = 0; sb < 4; sb++) {
          int d = sb * 32 + l31;
          short8 vf = *(const short8*)&Vb[d * 64 + (((kc2 * 32 + hi * 16) ^ ((d & 7) << 4)) >> 1)];
          accO[sb] = __builtin_amdgcn_mfma_f32_32x32x16_bf16(vf, pa, accO[sb], 0, 0, 0);
        }
        __builtin_amdgcn_s_setprio(0);
      }
    }
    __builtin_amdgcn_sched_barrier(0);
    asm volatile("s_waitcnt lgkmcnt(0)" ::: "memory");
    __builtin_amdgcn_s_barrier();
    __builtin_amdgcn_sched_barrier(0);
  }

  float rl = 1.0f / lsum;
  size_t orow = ((size_t)b * T_ + qg) * (H_*HD_) + hd * 128;
  #pragma unroll
  for (int sb = 0; sb < 4; sb++)
    #pragma unroll
    for (int g = 0; g < 4; g++) {
      ushort4 o;
      o.x = f2b_hw(accO[sb][4 * g + 0] * rl);
      o.y = f2b_hw(accO[sb][4 * g + 1] * rl);
      o.z = f2b_hw(accO[sb][4 * g + 2] * rl);
      o.w = f2b_hw(accO[sb][4 * g + 3] * rl);
      *(ushort4*)&ao[orow + sb * 32 + 8 * g + 4 * hi] = o;
    }
#undef REG_LOAD
#undef DS_WRITE
}

// ---------------- launcher ----------------
extern "C" void kernel_launch(void* const* d_in, const int* in_sizes, int n_in,
                              void* d_out, int out_size, void* d_ws, size_t ws_size,
                              hipStream_t stream)
{
  (void)in_sizes; (void)n_in; (void)out_size; (void)ws_size;
  const float* x        = (const float*)d_in[0];
  const float* Wq_down  = (const float*)d_in[1];
  const float* Wq_up    = (const float*)d_in[2];
  const float* Wq_rope  = (const float*)d_in[3];
  const float* Wkv_down = (const float*)d_in[4];
  const float* Wk_up    = (const float*)d_in[5];
  const float* Wv_up    = (const float*)d_in[6];
  const float* Wk_rope  = (const float*)d_in[7];
  const float* Wo       = (const float*)d_in[8];

  char* ws = (char*)d_ws;
  unsigned short* xb      = (unsigned short*)(ws + 0);          // [4096,2048] 16 MB
  unsigned short* Wdall   = (unsigned short*)(ws + 16777216);   // [3072,2048] 12 MB
  unsigned short* WquT    = (unsigned short*)(ws + 29360128);   // [1024,512]  1 MB (contig with WkcvT)
  unsigned short* WkcvT   = (unsigned short*)(ws + 30408704);   // [3072,512]  3 MB
  unsigned short* WoT     = (unsigned short*)(ws + 33554432);   // [2048,2048] 8 MB
  unsigned short* projall = (unsigned short*)(ws + 41943040);   // [4096,1024] 8 MB (latent only)
  unsigned short* qh      = (unsigned short*)(ws + 67108864);   // [B,H,T,128] 16 MB
  unsigned short* kh      = (unsigned short*)(ws + 83886080);   // 16 MB
  unsigned short* vt      = (unsigned short*)(ws + 100663296);  // [B,H,128,T] 16 MB
  unsigned short* ao      = (unsigned short*)(ws + 117440512);  // [4096,2048] 16 MB
  float2*         ctab    = (float2*)(ws + 134217728);          // [2048,32]   512 KB

  TT8 tab;
  int blk = 0;
  tab.e[0] = { Wq_down,  Wdall,               DM_, QR_,     blk }; blk += (QR_/32)*(DM_/32);
  tab.e[1] = { Wkv_down, Wdall + 512*2048,    DM_, DL_,     blk }; blk += (DL_/32)*(DM_/32);
  tab.e[2] = { Wq_rope,  Wdall + 1024*2048,   DM_, H_*RD_,  blk }; blk += (H_*RD_/32)*(DM_/32);
  tab.e[3] = { Wk_rope,  Wdall + 2048*2048,   DM_, H_*RD_,  blk }; blk += (H_*RD_/32)*(DM_/32);
  tab.e[4] = { Wq_up,    WquT,                QR_, H_*CD_,  blk }; blk += (H_*CD_/32)*(QR_/32);
  tab.e[5] = { Wk_up,    WkcvT,               DL_, H_*CD_,  blk }; blk += (H_*CD_/32)*(DL_/32);
  tab.e[6] = { Wv_up,    WkcvT + 1024*512,    DL_, H_*HD_,  blk }; blk += (H_*HD_/32)*(DL_/32);
  tab.e[7] = { Wo,       WoT,                 H_*HD_, DM_,  blk }; blk += (DM_/32)*(H_*HD_/32);

  // fused: cast (8192) + rope table (256) + all weight transposes (blk)
  prep_all<<<8192 + 256 + blk, 256, 0, stream>>>(x, xb, M_TOT * DM_, ctab, tab);

  gemm256<4><<<dim3(3072/256, M_TOT/256), 512, 0, stream>>>(
      xb, DM_, Wdall, projall, qh, kh, ctab, 1024, 3072, DM_);
  gemm256<5><<<dim3(4096/256, M_TOT/256), 512, 0, stream>>>(
      projall, 1024, WquT, qh, kh, vt, nullptr, 0, 4096, DL_);

  attn_fwd8<<<dim3(16, 32), 256, 0, stream>>>(qh, kh, vt, ao);

  gemm_out<<<dim3(DM_/256, M_TOT/128), 512, 0, stream>>>(
      ao, 2048, WoT, (float*)d_out, DM_, H_*HD_);
}

// Round 21
// 290.330 us; speedup vs baseline: 1.0031x; 1.0031x over previous
//
#include <hip/hip_runtime.h>
#include <hip/hip_bf16.h>
#include <stdint.h>
#include <math.h>

#define H_ 16
#define HD_ 128
#define RD_ 64
#define CD_ 64
#define DM_ 2048
#define QR_ 512
#define DL_ 512
#define B_ 2
#define T_ 2048
#define M_TOT (B_*T_)

typedef __attribute__((ext_vector_type(8))) short short8;
typedef __attribute__((ext_vector_type(4))) float f32x4;
typedef __attribute__((ext_vector_type(16))) float f32x16;

__device__ __forceinline__ unsigned short f2b_hw(float f){
  __hip_bfloat16 h = __float2bfloat16(f);
  union { __hip_bfloat16 h; unsigned short u; } c; c.h = h; return c.u;
}
__device__ __forceinline__ float b2f(unsigned short b){
  union { unsigned u; float f; } a; a.u = ((unsigned)b) << 16;
  return a.f;
}
__device__ __forceinline__ unsigned pack2(float lo, float hi){
  __hip_bfloat162 h2 = __float22bfloat162_rn(make_float2(lo, hi));
  union { __hip_bfloat162 h; unsigned u; } c; c.h = h2; return c.u;
}

#define GLOAD16(g, l) __builtin_amdgcn_global_load_lds( \
    (__attribute__((address_space(1))) void*)(g), \
    (__attribute__((address_space(3))) void*)(l), 16, 0, 0)

struct TTe { const float* src; unsigned short* dst; int K, N, blk0; };
struct TT8 { TTe e[8]; };

// ---------------- fused prep: x cast | rope table | 8 weight transposes ----------------
__global__ void prep_all(const float* __restrict__ src,
                         unsigned short* __restrict__ dst, int n,
                         float2* __restrict__ tab, TT8 tt){
  __shared__ float tile[32][33];
  int bid = blockIdx.x;
  int tid = threadIdx.x;
  if (bid < 8192) {
    int i = (bid * 256 + tid) * 4;
    if (i < n){
      float4 v = *(const float4*)(src + i);
      ushort4 o;
      o.x = f2b_hw(v.x); o.y = f2b_hw(v.y); o.z = f2b_hw(v.z); o.w = f2b_hw(v.w);
      *(ushort4*)(dst + i) = o;
    }
    return;
  }
  if (bid < 8448) {
    int idx = (bid - 8192) * 256 + tid;   // 64K entries
    int t = idx >> 5, j = idx & 31;
    float invf = exp2f(-(float)j * 0.4152410118750f);
    float fr = (float)t * invf;
    float s, c;
    sincosf(fr, &s, &c);
    tab[idx] = make_float2(c, s);
    return;
  }
  int loc = bid - 8448;
  const float* wsrc = tt.e[0].src;
  unsigned short* wdst = tt.e[0].dst;
  int K = tt.e[0].K, N = tt.e[0].N, l2 = loc;
  #pragma unroll
  for (int j = 1; j < 8; j++){
    if (loc >= tt.e[j].blk0){
      wsrc = tt.e[j].src; wdst = tt.e[j].dst;
      K = tt.e[j].K; N = tt.e[j].N; l2 = loc - tt.e[j].blk0;
    }
  }
  int cols = N / 32;
  int n0 = (l2 % cols) * 32, k0 = (l2 / cols) * 32;
  int tx = tid & 7, ty = tid >> 3;
  float4 v = *(const float4*)&wsrc[(size_t)(k0 + ty) * N + n0 + tx * 4];
  tile[ty][tx * 4 + 0] = v.x;
  tile[ty][tx * 4 + 1] = v.y;
  tile[ty][tx * 4 + 2] = v.z;
  tile[ty][tx * 4 + 3] = v.w;
  __syncthreads();
  ushort4 o;
  o.x = f2b_hw(tile[tx * 4 + 0][ty]);
  o.y = f2b_hw(tile[tx * 4 + 1][ty]);
  o.z = f2b_hw(tile[tx * 4 + 2][ty]);
  o.w = f2b_hw(tile[tx * 4 + 3][ty]);
  *(ushort4*)&wdst[(size_t)(n0 + ty) * K + k0 + tx * 4] = o;
}

// ---------------- 256x256 / BK=64 / 8-wave GEMM with counted vmcnt + st_16x32 swizzle ------
// MODE 4: N=3072 down-proj: cols<1024 -> latent linear; else fused-RoPE -> qh(Cv2)/kh(Cv3)
//         (q-rope pre-scaled by SC)
// MODE 5: N=4096 up-proj: cols<1024 -> qh content (pre-scaled by SC); <2048 -> kh; else vt^T
template<int MODE>
__global__ __launch_bounds__(512, 1) void gemm256(
    const unsigned short* __restrict__ A, int lda,
    const unsigned short* __restrict__ Bt,
    void* __restrict__ Cv, void* __restrict__ Cv2, void* __restrict__ Cv3,
    const float2* __restrict__ tab,
    int ldc, int N, int K)
{
  __shared__ __align__(16) unsigned short lds[65536];   // 128 KB
  char* ldsb = (char*)lds;

  const int tid = threadIdx.x;
  const int lane = tid & 63, w = tid >> 6;
  const int wm = w >> 2, wn = w & 3;
  const int l15 = lane & 15, kg = lane >> 4;

  int gx = gridDim.x;
  int nwg = gx * gridDim.y;
  int lin = blockIdx.x + gx * blockIdx.y;
  int q8 = nwg >> 3;
  int nl = (lin & 7) * q8 + (lin >> 3);
  int m0 = (nl / gx) * 256, n0 = (nl % gx) * 256;

  const unsigned short* Aeff = A;
  if (MODE == 5 && n0 >= 1024) Aeff = A + 512;

  const int srow = tid >> 3;
  const int scol = ((((tid & 7) << 4) ^ (((tid >> 5) & 1) << 5)) >> 1);
  const int aswz = ((l15 >> 2) & 1) << 5;

#define STG(bufb, kt) do {                                                     \
    int k0_ = (kt) * 64;                                                       \
    _Pragma("unroll")                                                          \
    for (int h_ = 0; h_ < 2; h_++)                                             \
      _Pragma("unroll")                                                        \
      for (int i_ = 0; i_ < 2; i_++) {                                         \
        GLOAD16(Aeff + (size_t)(m0 + h_*128 + i_*64 + srow) * lda + k0_ + scol,\
                ldsb + (bufb)*65536 + h_*16384 + i_*8192 + tid*16);            \
        GLOAD16(Bt + (size_t)(n0 + h_*128 + i_*64 + srow) * K + k0_ + scol,    \
                ldsb + (bufb)*65536 + 32768 + h_*16384 + i_*8192 + tid*16);    \
      }                                                                        \
  } while (0)

  f32x4 acc[8][4];
  #pragma unroll
  for (int i = 0; i < 8; i++)
    #pragma unroll
    for (int j = 0; j < 4; j++)
      acc[i][j] = (f32x4){0.f, 0.f, 0.f, 0.f};

  const int nK = K >> 6;
  STG(0, 0);
  STG(1, 1);

  for (int t = 0; t < nK; t++) {
    const int c = t & 1;
    if (t < nK - 1) { asm volatile("s_waitcnt vmcnt(8)" ::: "memory"); }
    else            { asm volatile("s_waitcnt vmcnt(0)" ::: "memory"); }
    __builtin_amdgcn_s_barrier();
    __builtin_amdgcn_sched_barrier(0);

    const char* bufA = ldsb + c * 65536 + wm * 16384;
    const char* bufB = ldsb + c * 65536 + 32768;

    short8 bfr[4][2];
    #pragma unroll
    for (int nf = 0; nf < 4; nf++) {
      int nr = wn * 64 + nf * 16 + l15;
      #pragma unroll
      for (int kk = 0; kk < 2; kk++) {
        int L = (nr & 127) * 128 + kk * 64 + kg * 16;
        bfr[nf][kk] = *(const short8*)(bufB + (nr >> 7) * 16384 + (L ^ aswz));
      }
    }
    __builtin_amdgcn_s_setprio(1);
    #pragma unroll
    for (int mh = 0; mh < 2; mh++) {
      short8 afr[4][2];
      #pragma unroll
      for (int q = 0; q < 4; q++) {
        int mf = mh * 4 + q;
        #pragma unroll
        for (int kk = 0; kk < 2; kk++) {
          int L = (mf * 16 + l15) * 128 + kk * 64 + kg * 16;
          afr[q][kk] = *(const short8*)(bufA + (L ^ aswz));
        }
      }
      #pragma unroll
      for (int q = 0; q < 4; q++)
        #pragma unroll
        for (int nf = 0; nf < 4; nf++)
          #pragma unroll
          for (int kk = 0; kk < 2; kk++)
            acc[mh*4+q][nf] = __builtin_amdgcn_mfma_f32_16x16x32_bf16(
                afr[q][kk], bfr[nf][kk], acc[mh*4+q][nf], 0, 0, 0);
    }
    __builtin_amdgcn_s_setprio(0);
    __builtin_amdgcn_sched_barrier(0);
    __builtin_amdgcn_s_barrier();
    __builtin_amdgcn_sched_barrier(0);
    if (t + 2 < nK) STG(c, t + 2);
  }
#undef STG

  if (MODE == 4) {
    if (n0 < 1024) {
      unsigned short* C = (unsigned short*)Cv;
      #pragma unroll
      for (int mf = 0; mf < 8; mf++)
        #pragma unroll
        for (int nf = 0; nf < 4; nf++)
          #pragma unroll
          for (int rr = 0; rr < 4; rr++) {
            int row = m0 + wm * 128 + mf * 16 + kg * 4 + rr;
            int col = n0 + wn * 64 + nf * 16 + l15;
            C[(size_t)row * ldc + col] = f2b_hw(acc[mf][nf][rr]);
          }
    } else {
      const bool isq = (n0 < 2048);
      unsigned short* dst = (unsigned short*)(isq ? Cv2 : Cv3);
      const float qsc = isq ? 0.12751743f : 1.0f;   // fold softmax scale into q
      int hbase = ((n0 - (isq ? 1024 : 2048)) >> 6) + wn;
      #pragma unroll
      for (int nf = 0; nf < 2; nf++) {
        int jr = nf * 16 + l15;
        #pragma unroll
        for (int mf = 0; mf < 8; mf++)
          #pragma unroll
          for (int rr = 0; rr < 4; rr++) {
            int gr = m0 + wm * 128 + mf * 16 + kg * 4 + rr;
            int tt = gr & (T_ - 1), bb = gr >> 11;
            float2 cs = tab[tt * 32 + jr];
            float x1 = acc[mf][nf][rr], x2 = acc[mf][nf + 2][rr];
            size_t base = ((size_t)(bb * H_ + hbase) * T_ + tt) * 128 + 64;
            dst[base + jr]      = f2b_hw((x1 * cs.x - x2 * cs.y) * qsc);
            dst[base + jr + 32] = f2b_hw((x1 * cs.y + x2 * cs.x) * qsc);
          }
      }
    }
  } else { // MODE 5
    if (n0 < 2048) {
      unsigned short* dstp = (unsigned short*)(n0 < 1024 ? Cv : Cv2);
      const float qsc = (n0 < 1024) ? 0.12751743f : 1.0f;  // q content pre-scaled
      int cb0 = n0 - (n0 < 1024 ? 0 : 1024);
      #pragma unroll
      for (int nf = 0; nf < 4; nf++) {
        int colb = cb0 + wn * 64 + nf * 16 + l15;
        int h = colb >> 6, d = colb & 63;
        #pragma unroll
        for (int mf = 0; mf < 8; mf++)
          #pragma unroll
          for (int rr = 0; rr < 4; rr++) {
            int gr = m0 + wm * 128 + mf * 16 + kg * 4 + rr;
            size_t idx = ((size_t)((gr >> 11) * H_ + h) * T_ + (gr & (T_-1))) * 128 + d;
            dstp[idx] = f2b_hw(acc[mf][nf][rr] * qsc);
          }
      }
    } else {
      unsigned short* vtp = (unsigned short*)Cv3;
      #pragma unroll
      for (int nf = 0; nf < 4; nf++) {
        int c2 = n0 + wn * 64 + nf * 16 + l15 - 2048;
        int h = c2 >> 7, d = c2 & 127;
        #pragma unroll
        for (int mf = 0; mf < 8; mf++) {
          int gr0 = m0 + wm * 128 + mf * 16 + kg * 4;
          int bb = gr0 >> 11, t0 = gr0 & (T_-1);
          ushort4 o;
          o.x = f2b_hw(acc[mf][nf][0]); o.y = f2b_hw(acc[mf][nf][1]);
          o.z = f2b_hw(acc[mf][nf][2]); o.w = f2b_hw(acc[mf][nf][3]);
          *(ushort4*)&vtp[((size_t)(bb * H_ + h) * 128 + d) * T_ + t0] = o;
        }
      }
    }
  }
}

// ---------------- output GEMM: 128x256 / BK=64 / 8-wave, f32 linear out ----------------
__global__ __launch_bounds__(512, 1) void gemm_out(
    const unsigned short* __restrict__ A, int lda,
    const unsigned short* __restrict__ Bt,
    float* __restrict__ C, int ldc, int K)
{
  __shared__ __align__(16) unsigned short lds[49152];
  char* ldsb = (char*)lds;

  const int tid = threadIdx.x;
  const int lane = tid & 63, w = tid >> 6;
  const int wm = w >> 2, wn = w & 3;
  const int l15 = lane & 15, kg = lane >> 4;

  int gx = gridDim.x;
  int nwg = gx * gridDim.y;
  int lin = blockIdx.x + gx * blockIdx.y;
  int q8 = nwg >> 3;
  int nl = (lin & 7) * q8 + (lin >> 3);
  int m0 = (nl / gx) * 128, n0 = (nl % gx) * 256;

  const int srow = tid >> 3;
  const int scol = ((((tid & 7) << 4) ^ (((tid >> 5) & 1) << 5)) >> 1);
  const int aswz = ((l15 >> 2) & 1) << 5;

#define STG(bufb, kt) do {                                                     \
    int k0_ = (kt) * 64;                                                       \
    _Pragma("unroll")                                                          \
    for (int i_ = 0; i_ < 2; i_++)                                             \
      GLOAD16(A + (size_t)(m0 + i_*64 + srow) * lda + k0_ + scol,              \
              ldsb + (bufb)*49152 + i_*8192 + tid*16);                         \
    _Pragma("unroll")                                                          \
    for (int i_ = 0; i_ < 4; i_++)                                             \
      GLOAD16(Bt + (size_t)(n0 + i_*64 + srow) * K + k0_ + scol,               \
              ldsb + (bufb)*49152 + 16384 + i_*8192 + tid*16);                 \
  } while (0)

  f32x4 acc[4][4];
  #pragma unroll
  for (int i = 0; i < 4; i++)
    #pragma unroll
    for (int j = 0; j < 4; j++)
      acc[i][j] = (f32x4){0.f, 0.f, 0.f, 0.f};

  const int nK = K >> 6;
  STG(0, 0);
  STG(1, 1);

  for (int t = 0; t < nK; t++) {
    const int c = t & 1;
    if (t < nK - 1) { asm volatile("s_waitcnt vmcnt(6)" ::: "memory"); }
    else            { asm volatile("s_waitcnt vmcnt(0)" ::: "memory"); }
    __builtin_amdgcn_s_barrier();
    __builtin_amdgcn_sched_barrier(0);

    const char* bufA = ldsb + c * 49152 + wm * 8192;
    const char* bufB = ldsb + c * 49152 + 16384;

    short8 bfr[4][2];
    #pragma unroll
    for (int nf = 0; nf < 4; nf++) {
      int nr = wn * 64 + nf * 16 + l15;
      #pragma unroll
      for (int kk = 0; kk < 2; kk++) {
        int L = (nr & 63) * 128 + kk * 64 + kg * 16;
        bfr[nf][kk] = *(const short8*)(bufB + (nr >> 6) * 8192 + (L ^ aswz));
      }
    }
    short8 afr[4][2];
    #pragma unroll
    for (int mf = 0; mf < 4; mf++)
      #pragma unroll
      for (int kk = 0; kk < 2; kk++) {
        int L = (mf * 16 + l15) * 128 + kk * 64 + kg * 16;
        afr[mf][kk] = *(const short8*)(bufA + (L ^ aswz));
      }
    __builtin_amdgcn_s_setprio(1);
    #pragma unroll
    for (int mf = 0; mf < 4; mf++)
      #pragma unroll
      for (int nf = 0; nf < 4; nf++)
        #pragma unroll
        for (int kk = 0; kk < 2; kk++)
          acc[mf][nf] = __builtin_amdgcn_mfma_f32_16x16x32_bf16(
              afr[mf][kk], bfr[nf][kk], acc[mf][nf], 0, 0, 0);
    __builtin_amdgcn_s_setprio(0);
    __builtin_amdgcn_sched_barrier(0);
    __builtin_amdgcn_s_barrier();
    __builtin_amdgcn_sched_barrier(0);
    if (t + 2 < nK) STG(c, t + 2);
  }
#undef STG

  #pragma unroll
  for (int mf = 0; mf < 4; mf++)
    #pragma unroll
    for (int nf = 0; nf < 4; nf++)
      #pragma unroll
      for (int rr = 0; rr < 4; rr++) {
        int row = m0 + wm * 64 + mf * 16 + kg * 4 + rr;
        int col = n0 + wn * 64 + nf * 16 + l15;
        C[(size_t)row * ldc + col] = acc[mf][nf][rr];
      }
}

// ---------------- causal flash attention: R7 pipeline + 4-way QK^T ILP (q pre-scaled) --------
// Dual-robust causal pairing: adjacent-x pairs AND x/x+256 pairs are both complementary.
__global__ __launch_bounds__(256, 2) void attn_fwd8(
    const unsigned short* __restrict__ qh,
    const unsigned short* __restrict__ kh,
    const unsigned short* __restrict__ vt,
    unsigned short* __restrict__ ao)
{
  __shared__ __align__(16) unsigned short lds[4 * 8192];

  const int tid  = threadIdx.x;
  const int lane = tid & 63, w = tid >> 6;
  const int l31  = lane & 31, hi = lane >> 5;
  const int bh = blockIdx.y;
  const int b  = bh >> 4, hd = bh & 15;
  // f(x): adjacent x -> complementary qt; bh-half flip: x/x+256 -> complementary qt.
  int qx = blockIdx.x;
  int qt = (qx & 1) ? (15 - (qx >> 1)) : (qx >> 1);
  if (bh >= 16) qt = 15 - qt;
  const int q0w   = qt * 128 + w * 32;
  const int qg    = q0w + l31;
  const int qmaxw = q0w + 31;
  const int nt    = 2 * qt + 2;

  const unsigned short* Qg = qh + (size_t)bh * T_ * 128;
  const unsigned short* Kg = kh + (size_t)bh * T_ * 128;
  const unsigned short* Vg = vt + (size_t)bh * 128 * T_;

  short8 qf[8];
  #pragma unroll
  for (int kc = 0; kc < 8; kc++)
    qf[kc] = *(const short8*)&Qg[(size_t)qg * 128 + kc * 16 + hi * 8];

  f32x16 accO[4];
  #pragma unroll
  for (int sb = 0; sb < 4; sb++)
    #pragma unroll
    for (int r = 0; r < 16; r++) accO[sb][r] = 0.f;

  float m = -1e30f, lsum = 0.f;
  // q is pre-scaled by (1/sqrt(128))*log2(e) at projection time -> scores already exp2-domain

  int krow[4], kwof[4], vrow[4], vwof[4];
  #pragma unroll
  for (int jj = 0; jj < 4; jj++){
    int r_ = (w * 4 + jj) * 4 + (lane >> 4);
    krow[jj] = r_;
    kwof[jj] = r_ * 128 + ((((lane & 15) * 16) ^ ((r_ & 7) << 4)) >> 1);
    int d_ = (w * 4 + jj) * 8 + (lane >> 3);
    vrow[jj] = d_;
    vwof[jj] = d_ * 64 + ((((lane & 7) * 16) ^ ((d_ & 7) << 4)) >> 1);
  }
  const int kcol = (lane & 15) * 8;
  const int vcol = (lane & 7) * 8;

  uint4 kst[4], vst[4];

#define REG_LOAD(kvt) do {                                                    \
    int kv0s = (kvt) * 64;                                                    \
    _Pragma("unroll")                                                         \
    for (int j_ = 0; j_ < 4; j_++) {                                          \
      kst[j_] = *(const uint4*)&Kg[(size_t)(kv0s + krow[j_]) * 128 + kcol];   \
      vst[j_] = *(const uint4*)&Vg[(size_t)vrow[j_] * T_ + kv0s + vcol];      \
    }                                                                         \
  } while (0)

#define DS_WRITE(bufi) do {                                                   \
    unsigned short* ksb_ = lds + (bufi) * 8192;                               \
    unsigned short* vsb_ = lds + 16384 + (bufi) * 8192;                       \
    _Pragma("unroll")                                                         \
    for (int j_ = 0; j_ < 4; j_++) {                                          \
      *(uint4*)&ksb_[kwof[j_]] = kst[j_];                                     \
      *(uint4*)&vsb_[vwof[j_]] = vst[j_];                                     \
    }                                                                         \
  } while (0)

  REG_LOAD(0);
  DS_WRITE(0);
  if (nt > 1) REG_LOAD(1);
  asm volatile("s_waitcnt lgkmcnt(0)" ::: "memory");
  __builtin_amdgcn_s_barrier();
  __builtin_amdgcn_sched_barrier(0);

  for (int t = 0; t < nt; t++) {
    const int cur = t & 1;
    if (t + 1 < nt) DS_WRITE(cur ^ 1);
    if (t + 2 < nt) REG_LOAD(t + 2);
    const int kv0 = t * 64;
    if (kv0 <= qmaxw) {
      const unsigned short* Kb = lds + cur * 8192;
      const unsigned short* Vb = lds + 16384 + cur * 8192;

      // ---- QK^T (swapped), 4 independent MFMA chains (a/b split) ----
      f32x16 sa0, sa1, sb0, sb1;
      #pragma unroll
      for (int r = 0; r < 16; r++) { sa0[r] = 0.f; sa1[r] = 0.f; sb0[r] = 0.f; sb1[r] = 0.f; }
      __builtin_amdgcn_s_setprio(1);
      #pragma unroll
      for (int kc = 0; kc < 8; kc += 2) {
        int co0 = (kc * 32 + hi * 16);
        int co1 = ((kc + 1) * 32 + hi * 16);
        int r0 = l31, r1 = 32 + l31;
        short8 kf0a = *(const short8*)&Kb[r0 * 128 + ((co0 ^ ((r0 & 7) << 4)) >> 1)];
        short8 kf1a = *(const short8*)&Kb[r1 * 128 + ((co0 ^ ((r1 & 7) << 4)) >> 1)];
        short8 kf0b = *(const short8*)&Kb[r0 * 128 + ((co1 ^ ((r0 & 7) << 4)) >> 1)];
        short8 kf1b = *(const short8*)&Kb[r1 * 128 + ((co1 ^ ((r1 & 7) << 4)) >> 1)];
        sa0 = __builtin_amdgcn_mfma_f32_32x32x16_bf16(kf0a, qf[kc], sa0, 0, 0, 0);
        sa1 = __builtin_amdgcn_mfma_f32_32x32x16_bf16(kf1a, qf[kc], sa1, 0, 0, 0);
        sb0 = __builtin_amdgcn_mfma_f32_32x32x16_bf16(kf0b, qf[kc + 1], sb0, 0, 0, 0);
        sb1 = __builtin_amdgcn_mfma_f32_32x32x16_bf16(kf1b, qf[kc + 1], sb1, 0, 0, 0);
      }
      __builtin_amdgcn_s_setprio(0);
      sa0 += sb0;
      sa1 += sb1;

      float p0[16], p1[16];
      float pmax = -1e30f;
      bool needMask = (kv0 + 63 > q0w);
      if (needMask) {
        #pragma unroll
        for (int r = 0; r < 16; r++) {
          int crow = (r & 3) + 8 * (r >> 2) + 4 * hi;
          float v0 = sa0[r];
          float v1 = sa1[r];
          if (kv0 + crow > qg)      v0 = -1e30f;
          if (kv0 + 32 + crow > qg) v1 = -1e30f;
          p0[r] = v0; p1[r] = v1;
          pmax = fmaxf(pmax, fmaxf(v0, v1));
        }
      } else {
        #pragma unroll
        for (int r = 0; r < 16; r++) {
          float v0 = sa0[r];
          float v1 = sa1[r];
          p0[r] = v0; p1[r] = v1;
          pmax = fmaxf(pmax, fmaxf(v0, v1));
        }
      }
      pmax = fmaxf(pmax, __shfl_xor(pmax, 32, 64));
      if (!__all(pmax <= m + 8.f)) {     // T13 defer-max
        float mn  = fmaxf(m, pmax);
        float fac = exp2f(m - mn);
        m = mn;
        lsum *= fac;
        #pragma unroll
        for (int sb = 0; sb < 4; sb++)
          #pragma unroll
          for (int r = 0; r < 16; r++) accO[sb][r] *= fac;
      }
      float ls = 0.f;
      #pragma unroll
      for (int r = 0; r < 16; r++) {
        p0[r] = exp2f(p0[r] - m);
        p1[r] = exp2f(p1[r] - m);
        ls += p0[r] + p1[r];
      }
      ls += __shfl_xor(ls, 32, 64);
      lsum += ls;

      #pragma unroll
      for (int kc2 = 0; kc2 < 4; kc2++) {
        unsigned A01, A23, B01, B23;
        if (kc2 == 0) { A01 = pack2(p0[0], p0[1]);  A23 = pack2(p0[2], p0[3]);
                        B01 = pack2(p0[4], p0[5]);  B23 = pack2(p0[6], p0[7]); }
        else if (kc2 == 1) { A01 = pack2(p0[8], p0[9]);   A23 = pack2(p0[10], p0[11]);
                             B01 = pack2(p0[12], p0[13]); B23 = pack2(p0[14], p0[15]); }
        else if (kc2 == 2) { A01 = pack2(p1[0], p1[1]);  A23 = pack2(p1[2], p1[3]);
                             B01 = pack2(p1[4], p1[5]);  B23 = pack2(p1[6], p1[7]); }
        else { A01 = pack2(p1[8], p1[9]);   A23 = pack2(p1[10], p1[11]);
               B01 = pack2(p1[12], p1[13]); B23 = pack2(p1[14], p1[15]); }
        asm("v_permlane32_swap_b32 %0, %1" : "+v"(A01), "+v"(B01));
        asm("v_permlane32_swap_b32 %0, %1" : "+v"(A23), "+v"(B23));
        union { unsigned u[4]; short8 v; } pk;
        pk.u[0] = A01; pk.u[1] = A23; pk.u[2] = B01; pk.u[3] = B23;
        short8 pa = pk.v;
        __builtin_amdgcn_s_setprio(1);
        #pragma unroll
        for (int sb = 0; sb < 4; sb++) {
          int d = sb * 32 + l31;
          short8 vf = *(const short8*)&Vb[d * 64 + (((kc2 * 32 + hi * 16) ^ ((d & 7) << 4)) >> 1)];
          accO[sb] = __builtin_amdgcn_mfma_f32_32x32x16_bf16(vf, pa, accO[sb], 0, 0, 0);
        }
        __builtin_amdgcn_s_setprio(0);
      }
    }
    __builtin_amdgcn_sched_barrier(0);
    asm volatile("s_waitcnt lgkmcnt(0)" ::: "memory");
    __builtin_amdgcn_s_barrier();
    __builtin_amdgcn_sched_barrier(0);
  }

  float rl = 1.0f / lsum;
  size_t orow = ((size_t)b * T_ + qg) * (H_*HD_) + hd * 128;
  #pragma unroll
  for (int sb = 0; sb < 4; sb++)
    #pragma unroll
    for (int g = 0; g < 4; g++) {
      ushort4 o;
      o.x = f2b_hw(accO[sb][4 * g + 0] * rl);
      o.y = f2b_hw(accO[sb][4 * g + 1] * rl);
      o.z = f2b_hw(accO[sb][4 * g + 2] * rl);
      o.w = f2b_hw(accO[sb][4 * g + 3] * rl);
      *(ushort4*)&ao[orow + sb * 32 + 8 * g + 4 * hi] = o;
    }
#undef REG_LOAD
#undef DS_WRITE
}

// ---------------- launcher ----------------
extern "C" void kernel_launch(void* const* d_in, const int* in_sizes, int n_in,
                              void* d_out, int out_size, void* d_ws, size_t ws_size,
                              hipStream_t stream)
{
  (void)in_sizes; (void)n_in; (void)out_size; (void)ws_size;
  const float* x        = (const float*)d_in[0];
  const float* Wq_down  = (const float*)d_in[1];
  const float* Wq_up    = (const float*)d_in[2];
  const float* Wq_rope  = (const float*)d_in[3];
  const float* Wkv_down = (const float*)d_in[4];
  const float* Wk_up    = (const float*)d_in[5];
  const float* Wv_up    = (const float*)d_in[6];
  const float* Wk_rope  = (const float*)d_in[7];
  const float* Wo       = (const float*)d_in[8];

  char* ws = (char*)d_ws;
  unsigned short* xb      = (unsigned short*)(ws + 0);          // [4096,2048] 16 MB
  unsigned short* Wdall   = (unsigned short*)(ws + 16777216);   // [3072,2048] 12 MB
  unsigned short* WquT    = (unsigned short*)(ws + 29360128);   // [1024,512]  1 MB (contig with WkcvT)
  unsigned short* WkcvT   = (unsigned short*)(ws + 30408704);   // [3072,512]  3 MB
  unsigned short* WoT     = (unsigned short*)(ws + 33554432);   // [2048,2048] 8 MB
  unsigned short* projall = (unsigned short*)(ws + 41943040);   // [4096,1024] 8 MB (latent only)
  unsigned short* qh      = (unsigned short*)(ws + 67108864);   // [B,H,T,128] 16 MB
  unsigned short* kh      = (unsigned short*)(ws + 83886080);   // 16 MB
  unsigned short* vt      = (unsigned short*)(ws + 100663296);  // [B,H,128,T] 16 MB
  unsigned short* ao      = (unsigned short*)(ws + 117440512);  // [4096,2048] 16 MB
  float2*         ctab    = (float2*)(ws + 134217728);          // [2048,32]   512 KB

  TT8 tab;
  int blk = 0;
  tab.e[0] = { Wq_down,  Wdall,               DM_, QR_,     blk }; blk += (QR_/32)*(DM_/32);
  tab.e[1] = { Wkv_down, Wdall + 512*2048,    DM_, DL_,     blk }; blk += (DL_/32)*(DM_/32);
  tab.e[2] = { Wq_rope,  Wdall + 1024*2048,   DM_, H_*RD_,  blk }; blk += (H_*RD_/32)*(DM_/32);
  tab.e[3] = { Wk_rope,  Wdall + 2048*2048,   DM_, H_*RD_,  blk }; blk += (H_*RD_/32)*(DM_/32);
  tab.e[4] = { Wq_up,    WquT,                QR_, H_*CD_,  blk }; blk += (H_*CD_/32)*(QR_/32);
  tab.e[5] = { Wk_up,    WkcvT,               DL_, H_*CD_,  blk }; blk += (H_*CD_/32)*(DL_/32);
  tab.e[6] = { Wv_up,    WkcvT + 1024*512,    DL_, H_*HD_,  blk }; blk += (H_*HD_/32)*(DL_/32);
  tab.e[7] = { Wo,       WoT,                 H_*HD_, DM_,  blk }; blk += (DM_/32)*(H_*HD_/32);

  // fused: cast (8192) + rope table (256) + all weight transposes (blk)
  prep_all<<<8192 + 256 + blk, 256, 0, stream>>>(x, xb, M_TOT * DM_, ctab, tab);

  gemm256<4><<<dim3(3072/256, M_TOT/256), 512, 0, stream>>>(
      xb, DM_, Wdall, projall, qh, kh, ctab, 1024, 3072, DM_);
  gemm256<5><<<dim3(4096/256, M_TOT/256), 512, 0, stream>>>(
      projall, 1024, WquT, qh, kh, vt, nullptr, 0, 4096, DL_);

  attn_fwd8<<<dim3(16, 32), 256, 0, stream>>>(qh, kh, vt, ao);

  gemm_out<<<dim3(DM_/256, M_TOT/128), 512, 0, stream>>>(
      ao, 2048, WoT, (float*)d_out, DM_, H_*HD_);
}

// Round 22
// 278.138 us; speedup vs baseline: 1.0471x; 1.0438x over previous
//
#include <hip/hip_runtime.h>
#include <hip/hip_bf16.h>
#include <stdint.h>
#include <math.h>

#define H_ 16
#define HD_ 128
#define RD_ 64
#define CD_ 64
#define DM_ 2048
#define QR_ 512
#define DL_ 512
#define B_ 2
#define T_ 2048
#define M_TOT (B_*T_)

typedef __attribute__((ext_vector_type(8))) short short8;
typedef __attribute__((ext_vector_type(4))) float f32x4;
typedef __attribute__((ext_vector_type(16))) float f32x16;

__device__ __forceinline__ unsigned short f2b_hw(float f){
  __hip_bfloat16 h = __float2bfloat16(f);
  union { __hip_bfloat16 h; unsigned short u; } c; c.h = h; return c.u;
}
__device__ __forceinline__ float b2f(unsigned short b){
  union { unsigned u; float f; } a; a.u = ((unsigned)b) << 16;
  return a.f;
}
__device__ __forceinline__ unsigned pack2(float lo, float hi){
  __hip_bfloat162 h2 = __float22bfloat162_rn(make_float2(lo, hi));
  union { __hip_bfloat162 h; unsigned u; } c; c.h = h2; return c.u;
}

#define GLOAD16(g, l) __builtin_amdgcn_global_load_lds( \
    (__attribute__((address_space(1))) void*)(g), \
    (__attribute__((address_space(3))) void*)(l), 16, 0, 0)

struct TTe { const float* src; unsigned short* dst; int K, N, blk0; };
struct TT8 { TTe e[8]; };

// ---------------- fused prep: x cast | rope table | 8 weight transposes ----------------
__global__ void prep_all(const float* __restrict__ src,
                         unsigned short* __restrict__ dst, int n,
                         float2* __restrict__ tab, TT8 tt){
  __shared__ float tile[32][33];
  int bid = blockIdx.x;
  int tid = threadIdx.x;
  if (bid < 8192) {
    int i = (bid * 256 + tid) * 4;
    if (i < n){
      float4 v = *(const float4*)(src + i);
      ushort4 o;
      o.x = f2b_hw(v.x); o.y = f2b_hw(v.y); o.z = f2b_hw(v.z); o.w = f2b_hw(v.w);
      *(ushort4*)(dst + i) = o;
    }
    return;
  }
  if (bid < 8448) {
    int idx = (bid - 8192) * 256 + tid;   // 64K entries
    int t = idx >> 5, j = idx & 31;
    float invf = exp2f(-(float)j * 0.4152410118750f);
    float fr = (float)t * invf;
    float s, c;
    sincosf(fr, &s, &c);
    tab[idx] = make_float2(c, s);
    return;
  }
  int loc = bid - 8448;
  const float* wsrc = tt.e[0].src;
  unsigned short* wdst = tt.e[0].dst;
  int K = tt.e[0].K, N = tt.e[0].N, l2 = loc;
  #pragma unroll
  for (int j = 1; j < 8; j++){
    if (loc >= tt.e[j].blk0){
      wsrc = tt.e[j].src; wdst = tt.e[j].dst;
      K = tt.e[j].K; N = tt.e[j].N; l2 = loc - tt.e[j].blk0;
    }
  }
  int cols = N / 32;
  int n0 = (l2 % cols) * 32, k0 = (l2 / cols) * 32;
  int tx = tid & 7, ty = tid >> 3;
  float4 v = *(const float4*)&wsrc[(size_t)(k0 + ty) * N + n0 + tx * 4];
  tile[ty][tx * 4 + 0] = v.x;
  tile[ty][tx * 4 + 1] = v.y;
  tile[ty][tx * 4 + 2] = v.z;
  tile[ty][tx * 4 + 3] = v.w;
  __syncthreads();
  ushort4 o;
  o.x = f2b_hw(tile[tx * 4 + 0][ty]);
  o.y = f2b_hw(tile[tx * 4 + 1][ty]);
  o.z = f2b_hw(tile[tx * 4 + 2][ty]);
  o.w = f2b_hw(tile[tx * 4 + 3][ty]);
  *(ushort4*)&wdst[(size_t)(n0 + ty) * K + k0 + tx * 4] = o;
}

// ---------------- 256x256 / BK=64 / 8-wave GEMM with counted vmcnt + st_16x32 swizzle ------
// MODE 4: N=3072 down-proj: cols<1024 -> latent linear; else fused-RoPE -> qh(Cv2)/kh(Cv3)
//         (q-rope pre-scaled by SC)
// MODE 5: N=4096 up-proj: cols<1024 -> qh content (pre-scaled by SC); <2048 -> kh; else vt^T
template<int MODE>
__global__ __launch_bounds__(512, 1) void gemm256(
    const unsigned short* __restrict__ A, int lda,
    const unsigned short* __restrict__ Bt,
    void* __restrict__ Cv, void* __restrict__ Cv2, void* __restrict__ Cv3,
    const float2* __restrict__ tab,
    int ldc, int N, int K)
{
  __shared__ __align__(16) unsigned short lds[65536];   // 128 KB
  char* ldsb = (char*)lds;

  const int tid = threadIdx.x;
  const int lane = tid & 63, w = tid >> 6;
  const int wm = w >> 2, wn = w & 3;
  const int l15 = lane & 15, kg = lane >> 4;

  int gx = gridDim.x;
  int nwg = gx * gridDim.y;
  int lin = blockIdx.x + gx * blockIdx.y;
  int q8 = nwg >> 3;
  int nl = (lin & 7) * q8 + (lin >> 3);
  int m0 = (nl / gx) * 256, n0 = (nl % gx) * 256;

  const unsigned short* Aeff = A;
  if (MODE == 5 && n0 >= 1024) Aeff = A + 512;

  const int srow = tid >> 3;
  const int scol = ((((tid & 7) << 4) ^ (((tid >> 5) & 1) << 5)) >> 1);
  const int aswz = ((l15 >> 2) & 1) << 5;

#define STG(bufb, kt) do {                                                     \
    int k0_ = (kt) * 64;                                                       \
    _Pragma("unroll")                                                          \
    for (int h_ = 0; h_ < 2; h_++)                                             \
      _Pragma("unroll")                                                        \
      for (int i_ = 0; i_ < 2; i_++) {                                         \
        GLOAD16(Aeff + (size_t)(m0 + h_*128 + i_*64 + srow) * lda + k0_ + scol,\
                ldsb + (bufb)*65536 + h_*16384 + i_*8192 + tid*16);            \
        GLOAD16(Bt + (size_t)(n0 + h_*128 + i_*64 + srow) * K + k0_ + scol,    \
                ldsb + (bufb)*65536 + 32768 + h_*16384 + i_*8192 + tid*16);    \
      }                                                                        \
  } while (0)

  f32x4 acc[8][4];
  #pragma unroll
  for (int i = 0; i < 8; i++)
    #pragma unroll
    for (int j = 0; j < 4; j++)
      acc[i][j] = (f32x4){0.f, 0.f, 0.f, 0.f};

  const int nK = K >> 6;
  STG(0, 0);
  STG(1, 1);

  for (int t = 0; t < nK; t++) {
    const int c = t & 1;
    if (t < nK - 1) { asm volatile("s_waitcnt vmcnt(8)" ::: "memory"); }
    else            { asm volatile("s_waitcnt vmcnt(0)" ::: "memory"); }
    __builtin_amdgcn_s_barrier();
    __builtin_amdgcn_sched_barrier(0);

    const char* bufA = ldsb + c * 65536 + wm * 16384;
    const char* bufB = ldsb + c * 65536 + 32768;

    short8 bfr[4][2];
    #pragma unroll
    for (int nf = 0; nf < 4; nf++) {
      int nr = wn * 64 + nf * 16 + l15;
      #pragma unroll
      for (int kk = 0; kk < 2; kk++) {
        int L = (nr & 127) * 128 + kk * 64 + kg * 16;
        bfr[nf][kk] = *(const short8*)(bufB + (nr >> 7) * 16384 + (L ^ aswz));
      }
    }
    __builtin_amdgcn_s_setprio(1);
    #pragma unroll
    for (int mh = 0; mh < 2; mh++) {
      short8 afr[4][2];
      #pragma unroll
      for (int q = 0; q < 4; q++) {
        int mf = mh * 4 + q;
        #pragma unroll
        for (int kk = 0; kk < 2; kk++) {
          int L = (mf * 16 + l15) * 128 + kk * 64 + kg * 16;
          afr[q][kk] = *(const short8*)(bufA + (L ^ aswz));
        }
      }
      #pragma unroll
      for (int q = 0; q < 4; q++)
        #pragma unroll
        for (int nf = 0; nf < 4; nf++)
          #pragma unroll
          for (int kk = 0; kk < 2; kk++)
            acc[mh*4+q][nf] = __builtin_amdgcn_mfma_f32_16x16x32_bf16(
                afr[q][kk], bfr[nf][kk], acc[mh*4+q][nf], 0, 0, 0);
    }
    __builtin_amdgcn_s_setprio(0);
    __builtin_amdgcn_sched_barrier(0);
    __builtin_amdgcn_s_barrier();
    __builtin_amdgcn_sched_barrier(0);
    if (t + 2 < nK) STG(c, t + 2);
  }
#undef STG

  if (MODE == 4) {
    if (n0 < 1024) {
      unsigned short* C = (unsigned short*)Cv;
      #pragma unroll
      for (int mf = 0; mf < 8; mf++)
        #pragma unroll
        for (int nf = 0; nf < 4; nf++)
          #pragma unroll
          for (int rr = 0; rr < 4; rr++) {
            int row = m0 + wm * 128 + mf * 16 + kg * 4 + rr;
            int col = n0 + wn * 64 + nf * 16 + l15;
            C[(size_t)row * ldc + col] = f2b_hw(acc[mf][nf][rr]);
          }
    } else {
      const bool isq = (n0 < 2048);
      unsigned short* dst = (unsigned short*)(isq ? Cv2 : Cv3);
      const float qsc = isq ? 0.12751743f : 1.0f;   // fold softmax scale into q
      int hbase = ((n0 - (isq ? 1024 : 2048)) >> 6) + wn;
      #pragma unroll
      for (int nf = 0; nf < 2; nf++) {
        int jr = nf * 16 + l15;
        #pragma unroll
        for (int mf = 0; mf < 8; mf++)
          #pragma unroll
          for (int rr = 0; rr < 4; rr++) {
            int gr = m0 + wm * 128 + mf * 16 + kg * 4 + rr;
            int tt = gr & (T_ - 1), bb = gr >> 11;
            float2 cs = tab[tt * 32 + jr];
            float x1 = acc[mf][nf][rr], x2 = acc[mf][nf + 2][rr];
            size_t base = ((size_t)(bb * H_ + hbase) * T_ + tt) * 128 + 64;
            dst[base + jr]      = f2b_hw((x1 * cs.x - x2 * cs.y) * qsc);
            dst[base + jr + 32] = f2b_hw((x1 * cs.y + x2 * cs.x) * qsc);
          }
      }
    }
  } else { // MODE 5
    if (n0 < 2048) {
      unsigned short* dstp = (unsigned short*)(n0 < 1024 ? Cv : Cv2);
      const float qsc = (n0 < 1024) ? 0.12751743f : 1.0f;  // q content pre-scaled
      int cb0 = n0 - (n0 < 1024 ? 0 : 1024);
      #pragma unroll
      for (int nf = 0; nf < 4; nf++) {
        int colb = cb0 + wn * 64 + nf * 16 + l15;
        int h = colb >> 6, d = colb & 63;
        #pragma unroll
        for (int mf = 0; mf < 8; mf++)
          #pragma unroll
          for (int rr = 0; rr < 4; rr++) {
            int gr = m0 + wm * 128 + mf * 16 + kg * 4 + rr;
            size_t idx = ((size_t)((gr >> 11) * H_ + h) * T_ + (gr & (T_-1))) * 128 + d;
            dstp[idx] = f2b_hw(acc[mf][nf][rr] * qsc);
          }
      }
    } else {
      unsigned short* vtp = (unsigned short*)Cv3;
      #pragma unroll
      for (int nf = 0; nf < 4; nf++) {
        int c2 = n0 + wn * 64 + nf * 16 + l15 - 2048;
        int h = c2 >> 7, d = c2 & 127;
        #pragma unroll
        for (int mf = 0; mf < 8; mf++) {
          int gr0 = m0 + wm * 128 + mf * 16 + kg * 4;
          int bb = gr0 >> 11, t0 = gr0 & (T_-1);
          ushort4 o;
          o.x = f2b_hw(acc[mf][nf][0]); o.y = f2b_hw(acc[mf][nf][1]);
          o.z = f2b_hw(acc[mf][nf][2]); o.w = f2b_hw(acc[mf][nf][3]);
          *(ushort4*)&vtp[((size_t)(bb * H_ + h) * 128 + d) * T_ + t0] = o;
        }
      }
    }
  }
}

// ---------------- output GEMM: 128x256 / BK=64 / 8-wave, f32 linear out ----------------
__global__ __launch_bounds__(512, 1) void gemm_out(
    const unsigned short* __restrict__ A, int lda,
    const unsigned short* __restrict__ Bt,
    float* __restrict__ C, int ldc, int K)
{
  __shared__ __align__(16) unsigned short lds[49152];
  char* ldsb = (char*)lds;

  const int tid = threadIdx.x;
  const int lane = tid & 63, w = tid >> 6;
  const int wm = w >> 2, wn = w & 3;
  const int l15 = lane & 15, kg = lane >> 4;

  int gx = gridDim.x;
  int nwg = gx * gridDim.y;
  int lin = blockIdx.x + gx * blockIdx.y;
  int q8 = nwg >> 3;
  int nl = (lin & 7) * q8 + (lin >> 3);
  int m0 = (nl / gx) * 128, n0 = (nl % gx) * 256;

  const int srow = tid >> 3;
  const int scol = ((((tid & 7) << 4) ^ (((tid >> 5) & 1) << 5)) >> 1);
  const int aswz = ((l15 >> 2) & 1) << 5;

#define STG(bufb, kt) do {                                                     \
    int k0_ = (kt) * 64;                                                       \
    _Pragma("unroll")                                                          \
    for (int i_ = 0; i_ < 2; i_++)                                             \
      GLOAD16(A + (size_t)(m0 + i_*64 + srow) * lda + k0_ + scol,              \
              ldsb + (bufb)*49152 + i_*8192 + tid*16);                         \
    _Pragma("unroll")                                                          \
    for (int i_ = 0; i_ < 4; i_++)                                             \
      GLOAD16(Bt + (size_t)(n0 + i_*64 + srow) * K + k0_ + scol,               \
              ldsb + (bufb)*49152 + 16384 + i_*8192 + tid*16);                 \
  } while (0)

  f32x4 acc[4][4];
  #pragma unroll
  for (int i = 0; i < 4; i++)
    #pragma unroll
    for (int j = 0; j < 4; j++)
      acc[i][j] = (f32x4){0.f, 0.f, 0.f, 0.f};

  const int nK = K >> 6;
  STG(0, 0);
  STG(1, 1);

  for (int t = 0; t < nK; t++) {
    const int c = t & 1;
    if (t < nK - 1) { asm volatile("s_waitcnt vmcnt(6)" ::: "memory"); }
    else            { asm volatile("s_waitcnt vmcnt(0)" ::: "memory"); }
    __builtin_amdgcn_s_barrier();
    __builtin_amdgcn_sched_barrier(0);

    const char* bufA = ldsb + c * 49152 + wm * 8192;
    const char* bufB = ldsb + c * 49152 + 16384;

    short8 bfr[4][2];
    #pragma unroll
    for (int nf = 0; nf < 4; nf++) {
      int nr = wn * 64 + nf * 16 + l15;
      #pragma unroll
      for (int kk = 0; kk < 2; kk++) {
        int L = (nr & 63) * 128 + kk * 64 + kg * 16;
        bfr[nf][kk] = *(const short8*)(bufB + (nr >> 6) * 8192 + (L ^ aswz));
      }
    }
    short8 afr[4][2];
    #pragma unroll
    for (int mf = 0; mf < 4; mf++)
      #pragma unroll
      for (int kk = 0; kk < 2; kk++) {
        int L = (mf * 16 + l15) * 128 + kk * 64 + kg * 16;
        afr[mf][kk] = *(const short8*)(bufA + (L ^ aswz));
      }
    __builtin_amdgcn_s_setprio(1);
    #pragma unroll
    for (int mf = 0; mf < 4; mf++)
      #pragma unroll
      for (int nf = 0; nf < 4; nf++)
        #pragma unroll
        for (int kk = 0; kk < 2; kk++)
          acc[mf][nf] = __builtin_amdgcn_mfma_f32_16x16x32_bf16(
              afr[mf][kk], bfr[nf][kk], acc[mf][nf], 0, 0, 0);
    __builtin_amdgcn_s_setprio(0);
    __builtin_amdgcn_sched_barrier(0);
    __builtin_amdgcn_s_barrier();
    __builtin_amdgcn_sched_barrier(0);
    if (t + 2 < nK) STG(c, t + 2);
  }
#undef STG

  #pragma unroll
  for (int mf = 0; mf < 4; mf++)
    #pragma unroll
    for (int nf = 0; nf < 4; nf++)
      #pragma unroll
      for (int rr = 0; rr < 4; rr++) {
        int row = m0 + wm * 64 + mf * 16 + kg * 4 + rr;
        int col = n0 + wn * 64 + nf * 16 + l15;
        C[(size_t)row * ldc + col] = acc[mf][nf][rr];
      }
}

// ---------------- causal flash attention: R7 pipeline + 4-way QK^T ILP (q pre-scaled) --------
// Dual-robust causal pairing: adjacent-x pairs AND x/x+256 pairs are both complementary.
__global__ __launch_bounds__(256, 2) void attn_fwd8(
    const unsigned short* __restrict__ qh,
    const unsigned short* __restrict__ kh,
    const unsigned short* __restrict__ vt,
    unsigned short* __restrict__ ao)
{
  __shared__ __align__(16) unsigned short lds[4 * 8192];

  const int tid  = threadIdx.x;
  const int lane = tid & 63, w = tid >> 6;
  const int l31  = lane & 31, hi = lane >> 5;
  const int bh = blockIdx.y;
  const int b  = bh >> 4, hd = bh & 15;
  // f(x): adjacent x -> complementary qt; bh-half flip: x/x+256 -> complementary qt.
  int qx = blockIdx.x;
  int qt = (qx & 1) ? (15 - (qx >> 1)) : (qx >> 1);
  if (bh >= 16) qt = 15 - qt;
  const int q0w   = qt * 128 + w * 32;
  const int qg    = q0w + l31;
  const int qmaxw = q0w + 31;
  const int nt    = 2 * qt + 2;

  const unsigned short* Qg = qh + (size_t)bh * T_ * 128;
  const unsigned short* Kg = kh + (size_t)bh * T_ * 128;
  const unsigned short* Vg = vt + (size_t)bh * 128 * T_;

  short8 qf[8];
  #pragma unroll
  for (int kc = 0; kc < 8; kc++)
    qf[kc] = *(const short8*)&Qg[(size_t)qg * 128 + kc * 16 + hi * 8];

  f32x16 accO[4];
  #pragma unroll
  for (int sb = 0; sb < 4; sb++)
    #pragma unroll
    for (int r = 0; r < 16; r++) accO[sb][r] = 0.f;

  float m = -1e30f, lsum = 0.f;
  // q is pre-scaled by (1/sqrt(128))*log2(e) at projection time -> scores already exp2-domain

  int krow[4], kwof[4], vrow[4], vwof[4];
  #pragma unroll
  for (int jj = 0; jj < 4; jj++){
    int r_ = (w * 4 + jj) * 4 + (lane >> 4);
    krow[jj] = r_;
    kwof[jj] = r_ * 128 + ((((lane & 15) * 16) ^ ((r_ & 7) << 4)) >> 1);
    int d_ = (w * 4 + jj) * 8 + (lane >> 3);
    vrow[jj] = d_;
    vwof[jj] = d_ * 64 + ((((lane & 7) * 16) ^ ((d_ & 7) << 4)) >> 1);
  }
  const int kcol = (lane & 15) * 8;
  const int vcol = (lane & 7) * 8;

  uint4 kst[4], vst[4];

#define REG_LOAD(kvt) do {                                                    \
    int kv0s = (kvt) * 64;                                                    \
    _Pragma("unroll")                                                         \
    for (int j_ = 0; j_ < 4; j_++) {                                          \
      kst[j_] = *(const uint4*)&Kg[(size_t)(kv0s + krow[j_]) * 128 + kcol];   \
      vst[j_] = *(const uint4*)&Vg[(size_t)vrow[j_] * T_ + kv0s + vcol];      \
    }                                                                         \
  } while (0)

#define DS_WRITE(bufi) do {                                                   \
    unsigned short* ksb_ = lds + (bufi) * 8192;                               \
    unsigned short* vsb_ = lds + 16384 + (bufi) * 8192;                       \
    _Pragma("unroll")                                                         \
    for (int j_ = 0; j_ < 4; j_++) {                                          \
      *(uint4*)&ksb_[kwof[j_]] = kst[j_];                                     \
      *(uint4*)&vsb_[vwof[j_]] = vst[j_];                                     \
    }                                                                         \
  } while (0)

  REG_LOAD(0);
  DS_WRITE(0);
  if (nt > 1) REG_LOAD(1);
  asm volatile("s_waitcnt lgkmcnt(0)" ::: "memory");
  __builtin_amdgcn_s_barrier();
  __builtin_amdgcn_sched_barrier(0);

  for (int t = 0; t < nt; t++) {
    const int cur = t & 1;
    if (t + 1 < nt) DS_WRITE(cur ^ 1);
    if (t + 2 < nt) REG_LOAD(t + 2);
    const int kv0 = t * 64;
    if (kv0 <= qmaxw) {
      const unsigned short* Kb = lds + cur * 8192;
      const unsigned short* Vb = lds + 16384 + cur * 8192;

      // ---- QK^T (swapped), 4 independent MFMA chains (a/b split) ----
      f32x16 sa0, sa1, sb0, sb1;
      #pragma unroll
      for (int r = 0; r < 16; r++) { sa0[r] = 0.f; sa1[r] = 0.f; sb0[r] = 0.f; sb1[r] = 0.f; }
      __builtin_amdgcn_s_setprio(1);
      #pragma unroll
      for (int kc = 0; kc < 8; kc += 2) {
        int co0 = (kc * 32 + hi * 16);
        int co1 = ((kc + 1) * 32 + hi * 16);
        int r0 = l31, r1 = 32 + l31;
        short8 kf0a = *(const short8*)&Kb[r0 * 128 + ((co0 ^ ((r0 & 7) << 4)) >> 1)];
        short8 kf1a = *(const short8*)&Kb[r1 * 128 + ((co0 ^ ((r1 & 7) << 4)) >> 1)];
        short8 kf0b = *(const short8*)&Kb[r0 * 128 + ((co1 ^ ((r0 & 7) << 4)) >> 1)];
        short8 kf1b = *(const short8*)&Kb[r1 * 128 + ((co1 ^ ((r1 & 7) << 4)) >> 1)];
        sa0 = __builtin_amdgcn_mfma_f32_32x32x16_bf16(kf0a, qf[kc], sa0, 0, 0, 0);
        sa1 = __builtin_amdgcn_mfma_f32_32x32x16_bf16(kf1a, qf[kc], sa1, 0, 0, 0);
        sb0 = __builtin_amdgcn_mfma_f32_32x32x16_bf16(kf0b, qf[kc + 1], sb0, 0, 0, 0);
        sb1 = __builtin_amdgcn_mfma_f32_32x32x16_bf16(kf1b, qf[kc + 1], sb1, 0, 0, 0);
      }
      __builtin_amdgcn_s_setprio(0);
      sa0 += sb0;
      sa1 += sb1;

      float p0[16], p1[16];
      float pmax = -1e30f;
      bool needMask = (kv0 + 63 > q0w);
      if (needMask) {
        #pragma unroll
        for (int r = 0; r < 16; r++) {
          int crow = (r & 3) + 8 * (r >> 2) + 4 * hi;
          float v0 = sa0[r];
          float v1 = sa1[r];
          if (kv0 + crow > qg)      v0 = -1e30f;
          if (kv0 + 32 + crow > qg) v1 = -1e30f;
          p0[r] = v0; p1[r] = v1;
          pmax = fmaxf(pmax, fmaxf(v0, v1));
        }
      } else {
        #pragma unroll
        for (int r = 0; r < 16; r++) {
          float v0 = sa0[r];
          float v1 = sa1[r];
          p0[r] = v0; p1[r] = v1;
          pmax = fmaxf(pmax, fmaxf(v0, v1));
        }
      }
      pmax = fmaxf(pmax, __shfl_xor(pmax, 32, 64));
      if (!__all(pmax <= m + 8.f)) {     // T13 defer-max
        float mn  = fmaxf(m, pmax);
        float fac = exp2f(m - mn);
        m = mn;
        lsum *= fac;
        #pragma unroll
        for (int sb = 0; sb < 4; sb++)
          #pragma unroll
          for (int r = 0; r < 16; r++) accO[sb][r] *= fac;
      }
      float ls = 0.f;
      #pragma unroll
      for (int r = 0; r < 16; r++) {
        p0[r] = exp2f(p0[r] - m);
        p1[r] = exp2f(p1[r] - m);
        ls += p0[r] + p1[r];
      }
      ls += __shfl_xor(ls, 32, 64);
      lsum += ls;

      #pragma unroll
      for (int kc2 = 0; kc2 < 4; kc2++) {
        unsigned A01, A23, B01, B23;
        if (kc2 == 0) { A01 = pack2(p0[0], p0[1]);  A23 = pack2(p0[2], p0[3]);
                        B01 = pack2(p0[4], p0[5]);  B23 = pack2(p0[6], p0[7]); }
        else if (kc2 == 1) { A01 = pack2(p0[8], p0[9]);   A23 = pack2(p0[10], p0[11]);
                             B01 = pack2(p0[12], p0[13]); B23 = pack2(p0[14], p0[15]); }
        else if (kc2 == 2) { A01 = pack2(p1[0], p1[1]);  A23 = pack2(p1[2], p1[3]);
                             B01 = pack2(p1[4], p1[5]);  B23 = pack2(p1[6], p1[7]); }
        else { A01 = pack2(p1[8], p1[9]);   A23 = pack2(p1[10], p1[11]);
               B01 = pack2(p1[12], p1[13]); B23 = pack2(p1[14], p1[15]); }
        asm("v_permlane32_swap_b32 %0, %1" : "+v"(A01), "+v"(B01));
        asm("v_permlane32_swap_b32 %0, %1" : "+v"(A23), "+v"(B23));
        union { unsigned u[4]; short8 v; } pk;
        pk.u[0] = A01; pk.u[1] = A23; pk.u[2] = B01; pk.u[3] = B23;
        short8 pa = pk.v;
        __builtin_amdgcn_s_setprio(1);
        #pragma unroll
        for (int sb = 0; sb < 4; sb++) {
          int d = sb * 32 + l31;
          short8 vf = *(const short8*)&Vb[d * 64 + (((kc2 * 32 + hi * 16) ^ ((d & 7) << 4)) >> 1)];
          accO[sb] = __builtin_amdgcn_mfma_f32_32x32x16_bf16(vf, pa, accO[sb], 0, 0, 0);
        }
        __builtin_amdgcn_s_setprio(0);
      }
    }
    __builtin_amdgcn_sched_barrier(0);
    asm volatile("s_waitcnt lgkmcnt(0)" ::: "memory");
    __builtin_amdgcn_s_barrier();
    __builtin_amdgcn_sched_barrier(0);
  }

  float rl = 1.0f / lsum;
  size_t orow = ((size_t)b * T_ + qg) * (H_*HD_) + hd * 128;
  #pragma unroll
  for (int sb = 0; sb < 4; sb++)
    #pragma unroll
    for (int g = 0; g < 4; g++) {
      ushort4 o;
      o.x = f2b_hw(accO[sb][4 * g + 0] * rl);
      o.y = f2b_hw(accO[sb][4 * g + 1] * rl);
      o.z = f2b_hw(accO[sb][4 * g + 2] * rl);
      o.w = f2b_hw(accO[sb][4 * g + 3] * rl);
      *(ushort4*)&ao[orow + sb * 32 + 8 * g + 4 * hi] = o;
    }
#undef REG_LOAD
#undef DS_WRITE
}

// ---------------- launcher ----------------
extern "C" void kernel_launch(void* const* d_in, const int* in_sizes, int n_in,
                              void* d_out, int out_size, void* d_ws, size_t ws_size,
                              hipStream_t stream)
{
  (void)in_sizes; (void)n_in; (void)out_size; (void)ws_size;
  const float* x        = (const float*)d_in[0];
  const float* Wq_down  = (const float*)d_in[1];
  const float* Wq_up    = (const float*)d_in[2];
  const float* Wq_rope  = (const float*)d_in[3];
  const float* Wkv_down = (const float*)d_in[4];
  const float* Wk_up    = (const float*)d_in[5];
  const float* Wv_up    = (const float*)d_in[6];
  const float* Wk_rope  = (const float*)d_in[7];
  const float* Wo       = (const float*)d_in[8];

  char* ws = (char*)d_ws;
  unsigned short* xb      = (unsigned short*)(ws + 0);          // [4096,2048] 16 MB
  unsigned short* Wdall   = (unsigned short*)(ws + 16777216);   // [3072,2048] 12 MB
  unsigned short* WquT    = (unsigned short*)(ws + 29360128);   // [1024,512]  1 MB (contig with WkcvT)
  unsigned short* WkcvT   = (unsigned short*)(ws + 30408704);   // [3072,512]  3 MB
  unsigned short* WoT     = (unsigned short*)(ws + 33554432);   // [2048,2048] 8 MB
  unsigned short* projall = (unsigned short*)(ws + 41943040);   // [4096,1024] 8 MB (latent only)
  unsigned short* qh      = (unsigned short*)(ws + 67108864);   // [B,H,T,128] 16 MB
  unsigned short* kh      = (unsigned short*)(ws + 83886080);   // 16 MB
  unsigned short* vt      = (unsigned short*)(ws + 100663296);  // [B,H,128,T] 16 MB
  unsigned short* ao      = (unsigned short*)(ws + 117440512);  // [4096,2048] 16 MB
  float2*         ctab    = (float2*)(ws + 134217728);          // [2048,32]   512 KB

  TT8 tab;
  int blk = 0;
  tab.e[0] = { Wq_down,  Wdall,               DM_, QR_,     blk }; blk += (QR_/32)*(DM_/32);
  tab.e[1] = { Wkv_down, Wdall + 512*2048,    DM_, DL_,     blk }; blk += (DL_/32)*(DM_/32);
  tab.e[2] = { Wq_rope,  Wdall + 1024*2048,   DM_, H_*RD_,  blk }; blk += (H_*RD_/32)*(DM_/32);
  tab.e[3] = { Wk_rope,  Wdall + 2048*2048,   DM_, H_*RD_,  blk }; blk += (H_*RD_/32)*(DM_/32);
  tab.e[4] = { Wq_up,    WquT,                QR_, H_*CD_,  blk }; blk += (H_*CD_/32)*(QR_/32);
  tab.e[5] = { Wk_up,    WkcvT,               DL_, H_*CD_,  blk }; blk += (H_*CD_/32)*(DL_/32);
  tab.e[6] = { Wv_up,    WkcvT + 1024*512,    DL_, H_*HD_,  blk }; blk += (H_*HD_/32)*(DL_/32);
  tab.e[7] = { Wo,       WoT,                 H_*HD_, DM_,  blk }; blk += (DM_/32)*(H_*HD_/32);

  // fused: cast (8192) + rope table (256) + all weight transposes (blk)
  prep_all<<<8192 + 256 + blk, 256, 0, stream>>>(x, xb, M_TOT * DM_, ctab, tab);

  gemm256<4><<<dim3(3072/256, M_TOT/256), 512, 0, stream>>>(
      xb, DM_, Wdall, projall, qh, kh, ctab, 1024, 3072, DM_);
  gemm256<5><<<dim3(4096/256, M_TOT/256), 512, 0, stream>>>(
      projall, 1024, WquT, qh, kh, vt, nullptr, 0, 4096, DL_);

  attn_fwd8<<<dim3(16, 32), 256, 0, stream>>>(qh, kh, vt, ao);

  gemm_out<<<dim3(DM_/256, M_TOT/128), 512, 0, stream>>>(
      ao, 2048, WoT, (float*)d_out, DM_, H_*HD_);
}